// Round 1
// baseline (1052.830 us; speedup 1.0000x reference)
//
#include <hip/hip_runtime.h>

#define C_   256
#define HW_  1024
#define N_   16384
#define K_   8192
#define BM   128
#define BN   128
#define BK   16
#define KSPLIT 8
#define KPB  (K_/KSPLIT)      /* 1024 K per block */
#define NKT  (KPB/BN)         /* 8 K-tiles per block */
#define OUT_SZ   4194304
#define LOSS_OFF 4194304
#define IDX_OFF  4194305

// Kernel 1: cnorm[k] = 0.5*||e_k||^2 ; also zero the loss slot (d_out is re-poisoned every call)
__global__ __launch_bounds__(256) void k_norms(const float* __restrict__ emb,
                                               float* __restrict__ cnorm,
                                               float* __restrict__ loss_slot) {
  int tid  = threadIdx.x;
  int wave = tid >> 6, lane = tid & 63;
  int k = blockIdx.x * 4 + wave;
  float4 v = *(const float4*)(emb + k * C_ + lane * 4);
  float s = v.x*v.x + v.y*v.y + v.z*v.z + v.w*v.w;
  #pragma unroll
  for (int m = 32; m > 0; m >>= 1) s += __shfl_xor(s, m);
  if (lane == 0) cnorm[k] = 0.5f * s;
  if (blockIdx.x == 0 && tid == 0) *loss_slot = 0.0f;
}

// Kernel 2: fused fp32 GEMM (score = f.e - 0.5||e||^2) + per-row running argmax over this
// block's K-range. 128x128 tile, BK=16, 8x8 micro-tile, 256 threads.
__global__ __launch_bounds__(256) void k_score(const float* __restrict__ inp,
                                               const float* __restrict__ emb,
                                               const float* __restrict__ cnorm,
                                               float* __restrict__ bestS,
                                               int*   __restrict__ bestK) {
  __shared__ float As[BK][BM + 4];   // [cc][m], stride 132 floats (16B-aligned rows)
  __shared__ float Bs[BK][BN + 4];   // [cc][k]

  const int tid = threadIdx.x;
  const int tx = tid & 15, ty = tid >> 4;
  const int rt = blockIdx.x >> 3;       // row tile 0..127
  const int ks = blockIdx.x & 7;        // K split 0..7 (adjacent blocks share the A tile in L2)
  const int row0 = rt * BM;             // BM=128 divides HW=1024 -> tile stays within one b
  const float* Abase = inp + (row0 >> 10) * (C_ * HW_) + (row0 & 1023);
  const int kbase = ks * KPB;

  const int m4  = (tid & 31) << 2;      // A staging: float4 along m
  const int ccA = tid >> 5;             // 0..7 (two passes cover cc 0..15)
  const int cc4 = (tid & 3) << 2;       // B staging: float4 along c, transpose into LDS
  const int kkB = tid >> 2;             // 0..63 (two passes cover k 0..127)

  float rS[8]; int rK[8];
  #pragma unroll
  for (int r = 0; r < 8; ++r) { rS[r] = -3.4e38f; rK[r] = 0; }

  for (int kt = 0; kt < NKT; ++kt) {
    const int k0 = kbase + kt * BN;
    float acc[8][8];
    #pragma unroll
    for (int r = 0; r < 8; ++r)
      #pragma unroll
      for (int c = 0; c < 8; ++c) acc[r][c] = 0.f;

    for (int ci = 0; ci < C_ / BK; ++ci) {
      const int c0 = ci * BK;
      __syncthreads();  // protect previous iteration's reads before overwrite
      #pragma unroll
      for (int p = 0; p < 2; ++p) {  // stage A: coalesced float4, contiguous LDS write
        int cc = ccA + p * 8;
        float4 v = *(const float4*)(Abase + (c0 + cc) * HW_ + m4);
        *(float4*)(&As[cc][m4]) = v;
      }
      #pragma unroll
      for (int p = 0; p < 2; ++p) {  // stage B: 16B global read, transposed scatter to LDS
        int k = kkB + p * 64;
        float4 v = *(const float4*)(emb + (k0 + k) * C_ + c0 + cc4);
        Bs[cc4 + 0][k] = v.x; Bs[cc4 + 1][k] = v.y;
        Bs[cc4 + 2][k] = v.z; Bs[cc4 + 3][k] = v.w;
      }
      __syncthreads();
      #pragma unroll
      for (int cc = 0; cc < BK; ++cc) {
        float4 a0 = *(const float4*)(&As[cc][ty * 8]);
        float4 a1 = *(const float4*)(&As[cc][ty * 8 + 4]);
        float4 b0 = *(const float4*)(&Bs[cc][tx * 8]);
        float4 b1 = *(const float4*)(&Bs[cc][tx * 8 + 4]);
        float a[8] = {a0.x, a0.y, a0.z, a0.w, a1.x, a1.y, a1.z, a1.w};
        float b[8] = {b0.x, b0.y, b0.z, b0.w, b1.x, b1.y, b1.z, b1.w};
        #pragma unroll
        for (int r = 0; r < 8; ++r)
          #pragma unroll
          for (int c = 0; c < 8; ++c) acc[r][c] += a[r] * b[c];
      }
    }
    // subtract 0.5||e||^2 and fold into running per-row argmax (ascending k, strict > keeps earliest)
    float cn[8];
    {
      float4 c0v = *(const float4*)(cnorm + k0 + tx * 8);
      float4 c1v = *(const float4*)(cnorm + k0 + tx * 8 + 4);
      cn[0] = c0v.x; cn[1] = c0v.y; cn[2] = c0v.z; cn[3] = c0v.w;
      cn[4] = c1v.x; cn[5] = c1v.y; cn[6] = c1v.z; cn[7] = c1v.w;
    }
    #pragma unroll
    for (int r = 0; r < 8; ++r)
      #pragma unroll
      for (int c = 0; c < 8; ++c) {
        float s = acc[r][c] - cn[c];
        if (s > rS[r]) { rS[r] = s; rK[r] = k0 + tx * 8 + c; }
      }
  }

  // cross-tx (16 contiguous lanes) argmax reduce; tie -> lower k (numpy first-min semantics)
  #pragma unroll
  for (int r = 0; r < 8; ++r) {
    float s = rS[r]; int kk = rK[r];
    #pragma unroll
    for (int m = 1; m < 16; m <<= 1) {
      float so = __shfl_xor(s, m);
      int   ko = __shfl_xor(kk, m);
      if (so > s || (so == s && ko < kk)) { s = so; kk = ko; }
    }
    if (tx == 0) {
      int row = row0 + ty * 8 + r;
      bestS[ks * N_ + row] = s;
      bestK[ks * N_ + row] = kk;
    }
  }
}

// Kernel 3: merge the KSPLIT candidates per row; splits are ascending in k so strict > keeps lowest k
__global__ __launch_bounds__(256) void k_merge(const float* __restrict__ bestS,
                                              const int*   __restrict__ bestK,
                                              float* __restrict__ out_idx,
                                              int*   __restrict__ fidx) {
  int n = blockIdx.x * 256 + threadIdx.x;
  float bs = -3.4e38f; int bk = 0x7fffffff;
  #pragma unroll
  for (int s = 0; s < KSPLIT; ++s) {
    float v = bestS[s * N_ + n];
    int  kk = bestK[s * N_ + n];
    if (v > bs || (v == bs && kk < bk)) { bs = v; bk = kk; }
  }
  out_idx[n] = (float)bk;
  fidx[n] = bk;
}

// Kernel 4: out[b][c][h][w] = emb[idx[n]][c] (coalesced writes), fused commitment-loss reduction
__global__ __launch_bounds__(256) void k_epilogue(const float* __restrict__ inp,
                                                  const float* __restrict__ emb,
                                                  const int*   __restrict__ fidx,
                                                  float* __restrict__ out,
                                                  float* __restrict__ loss) {
  int e  = blockIdx.x * 256 + threadIdx.x;
  int c  = (e >> 10) & 255;
  int b  = e >> 18;
  int hw = e & 1023;
  int n  = (b << 10) | hw;
  int kq = fidx[n];
  float q = emb[kq * C_ + c];
  float x = inp[e];
  out[e] = q;
  float p = (q - x) * (q - x);
  #pragma unroll
  for (int m = 32; m > 0; m >>= 1) p += __shfl_xor(p, m);
  __shared__ float red[4];
  int lane = threadIdx.x & 63, wv = threadIdx.x >> 6;
  if (lane == 0) red[wv] = p;
  __syncthreads();
  if (threadIdx.x == 0) {
    float t = (red[0] + red[1] + red[2] + red[3]) * (0.25f / (float)OUT_SZ);
    atomicAdd(loss, t);
  }
}

extern "C" void kernel_launch(void* const* d_in, const int* in_sizes, int n_in,
                              void* d_out, int out_size, void* d_ws, size_t ws_size,
                              hipStream_t stream) {
  const float* inp = (const float*)d_in[0];   // [16,256,32,32] fp32
  const float* emb = (const float*)d_in[1];   // [8192,256] fp32
  float* out = (float*)d_out;

  // workspace layout (~1.1 MB): cnorm | bestS[8][N] | bestK[8][N] | fidx[N]
  float* cnorm = (float*)d_ws;
  float* bestS = cnorm + K_;
  int*   bestK = (int*)(bestS + KSPLIT * N_);
  int*   fidx  = bestK + KSPLIT * N_;

  k_norms   <<<K_ / 4,            256, 0, stream>>>(emb, cnorm, out + LOSS_OFF);
  k_score   <<<(N_ / BM) * KSPLIT,256, 0, stream>>>(inp, emb, cnorm, bestS, bestK);
  k_merge   <<<N_ / 256,          256, 0, stream>>>(bestS, bestK, out + IDX_OFF, fidx);
  k_epilogue<<<OUT_SZ / 256,      256, 0, stream>>>(inp, emb, fidx, out, out + LOSS_OFF);
}